// Round 7
// baseline (137.955 us; speedup 1.0000x reference)
//
#include <hip/hip_runtime.h>
#include <stdint.h>

// VectorQuantizer on MI355X — round 13: cut LDS volume (32x32x16 MFMA, fat
// wave tiles) + pipeline phase A via DMA + prefetch phase-C latent.
// R7/R11/R12 all ~55-57 us across 3 different phase-B schedules => B is
// VOLUME-bound, not barrier-bound. Largest pipe floor = LDS (~20-22 us/CU:
// 3072 ds_read_b128 x 12cyc + 1MB DMA writes + phase-A round-trip).
// R13: (1) mfma 32x32x16, wave tile 64 pos x 64 codes (2a+2b reads -> 4
// MFMA per 16d chunk): block ds_reads 1536->1024, MFMA instrs 2048->1024,
// epilogue 2 sweeps x 1 shuffle. acc[2][2] f32x16 = 64 VGPR, live ~110 <
// 128 cap at (512,4). Swapped operands (rows=codes); C-layout per m74/m101.
// (2) Phase A: latent slabs DMA'd (global_load_lds) into Es bufs ([64][64]
// f32 = exactly 16 KB), DMA(s+1) under convert(s), STAGE_ES(0) fused into
// last A phase — removes serial HBM latency + reg round-trip.
// (3) Phase-C latent float4s issued before the bests barrier.
// NUMERICS NOTE: 32x32x16 sums 16 products/instr (vs 32) -> different fp32
// rounding -> a few argmin flips at near-ties; absmax expected to move from
// 0.001930 but stay ~0.002 scale (codes differ by <=~0.002/coord).
// latent [32,256,1024] fp32, codebook [1024,256] fp32.
// ws = [ Ebf bf16 chunk-planar [dq32][code1024][8] (512 KB) | e2 f32[1024] ].

#define D_   256
#define HW_  1024
#define N_   32768
#define K_   1024

typedef __attribute__((ext_vector_type(8)))  short s8v;   // 8 bf16 (4 VGPR)
typedef __attribute__((ext_vector_type(16))) float f16v;  // 32x32 MFMA acc

__device__ __forceinline__ ushort bf16rne(float x) {
  unsigned u = __float_as_uint(x);
  return (ushort)((u + 0x7FFFu + ((u >> 16) & 1u)) >> 16);
}

// monotone map: unsigned order of key == float order (handles negatives)
__device__ __forceinline__ unsigned fkey(float f) {
  unsigned u = __float_as_uint(f);
  return u ^ (unsigned)(((int)u >> 31) | 0x80000000);
}

// async global->LDS DMA, 16 B/lane; LDS dest = wave-uniform base + lane*16
__device__ __forceinline__ void gld_lds16(const void* g, void* l) {
  __builtin_amdgcn_global_load_lds(
      (const __attribute__((address_space(1))) unsigned int*)g,
      (__attribute__((address_space(3))) unsigned int*)l, 16, 0, 0);
}

// ---------- codebook -> bf16 chunk-planar Ebf + numpy-pairwise e2 + loss=0 ----------
// (unchanged from R12 — outputs bit-identical)
__global__ __launch_bounds__(256) void k_eprep(const float* __restrict__ cb,
                                               ushort* __restrict__ Ebf,
                                               float* __restrict__ e2,
                                               float* __restrict__ loss) {
  const int t = threadIdx.x, blk = blockIdx.x;   // 128 blocks x 8 codes
  if (blk == 0 && t == 0) *loss = 0.f;
  {
    int cl = t & 7, dq = t >> 3;                 // code-local 0..7, d-chunk 0..31
    const float* src = cb + (size_t)(blk * 8 + cl) * 256 + dq * 8;
    float4 v0 = ((const float4*)src)[0], v1 = ((const float4*)src)[1];
    ushort tmp[8] __attribute__((aligned(16)));
    tmp[0] = bf16rne(v0.x); tmp[1] = bf16rne(v0.y);
    tmp[2] = bf16rne(v0.z); tmp[3] = bf16rne(v0.w);
    tmp[4] = bf16rne(v1.x); tmp[5] = bf16rne(v1.y);
    tmp[6] = bf16rne(v1.z); tmp[7] = bf16rne(v1.w);
    *(uint4*)(Ebf + ((size_t)dq * 1024 + blk * 8 + cl) * 8) = *(uint4*)tmp;
  }
  // e2 numpy-pairwise: 16 lanes/row, butterfly reproduces pairwise tree
  if (t < 128) {
    const int row = blk * 8 + (t >> 4);
    const int sub = t & 15, j = sub & 7, h = sub >> 3;
    const float* base = cb + row * 256 + h * 128 + j;
    float r = __fmul_rn(base[0], base[0]);
    for (int i = 1; i < 16; ++i) {
      float v = base[8 * i];
      r = __fadd_rn(r, __fmul_rn(v, v));
    }
#pragma unroll
    for (int m = 1; m < 16; m <<= 1) r = __fadd_rn(r, __shfl_xor(r, m, 64));
    if (sub == 0) e2[row] = r;
  }
}

// ---------- fused: convert + MFMA-argmin over K=1024 + gather + out + loss ----------
// Grid 512 tiles (64 pos). Block 512 = 8 waves. LDS: Xbf 32 KB [dq32][pos64]
// [8]; Es 2x16 KB ([dqL2][code512][8] stages; phase-A Xf [64][64] f32
// overlay, exact fit); e2s 4 KB; bests 512 B -> ~69 KB -> 2 blocks/CU.
// 36 pipelined phases total: 4 A-slabs + 32 B-phases (2 sweeps x 16 chunks
// of 16 d). Wave w: 64 pos x 64 codes (codes w*64 within sweep), acc[2][2]
// f32x16, swapped operands (A-op = codes).
__global__ __launch_bounds__(512, 4) void k_fused(
    const float* __restrict__ latent, const float* __restrict__ cb,
    const ushort* __restrict__ Ebf, const float* __restrict__ e2g,
    float* __restrict__ out, float* __restrict__ loss) {
  __shared__ alignas(16) ushort Xbf[32 * 64 * 8];    // 32 KB
  __shared__ alignas(16) ushort Es[2][8192];         // 2x16 KB (+Xf overlay)
  __shared__ alignas(16) float e2s[1024];            // 4 KB
  __shared__ unsigned long long bests[64];           // 512 B
  __shared__ float red[8];

  const int t = threadIdx.x, tile = blockIdx.x;      // 512 tiles x 64 pos
  const int b = tile >> 4, hw0 = (tile & 15) * 64;
  const int lane = t & 63, w = t >> 6;               // wave 0..7
  const int l31 = lane & 31, hi = lane >> 5;

  ((float2*)e2s)[t] = ((const float2*)e2g)[t];       // 1024 floats, 512 thr
  if (t < 64) bests[t] = ~0ull;

  const float* Lb = latent + (size_t)b * (D_ * HW_) + hw0;

  // DMA latent slab S (64 d x 64 pos f32 = 16 KB) -> Es[S&1] as [d64][pos64]
#define DMA_XF(S)                                                         \
  {                                                                       \
    float* XfD = (float*)Es[(S) & 1];                                     \
    _Pragma("unroll")                                                     \
    for (int ii = 0; ii < 2; ++ii) {                                      \
      int jj = w * 2 + ii;                          /* 4 d-rows each */   \
      gld_lds16(Lb + (size_t)((S) * 64 + jj * 4 + (lane >> 4)) * HW_      \
                    + (lane & 15) * 4,                                    \
                XfD + jj * 256 + lane * 4);                               \
    }                                                                     \
  }

  // DMA codebook stage J (sweep J>>4, 16d-chunk J&15): 512 codes x 16 d
#define STAGE_ES(J)                                                       \
  {                                                                       \
    const int chS = (J) & 15, khS = ((J) >> 4) * 512, bufS = (J) & 1;     \
    _Pragma("unroll")                                                     \
    for (int ii = 0; ii < 2; ++ii) {                                      \
      int jj = w * 2 + ii;                                                \
      int dqL = jj >> 3, seg = jj & 7;                                    \
      gld_lds16(Ebf + ((size_t)(chS * 2 + dqL) * 1024 + khS + seg * 64    \
                       + lane) * 8,                                       \
                &Es[bufS][((size_t)dqL * 512 + seg * 64 + lane) * 8]);    \
    }                                                                     \
  }

  // ---- Phase A: 4 pipelined slabs; wave w converts d-chunk dqs=w ----
  DMA_XF(0);
#pragma unroll 1
  for (int s = 0; s < 4; ++s) {
    asm volatile("s_waitcnt vmcnt(0)" ::: "memory"); // my DMA(s) landed
    __builtin_amdgcn_sched_barrier(0);
    __builtin_amdgcn_s_barrier();                    // slab s fully in Es[s&1]
    __builtin_amdgcn_sched_barrier(0);
    if (s < 3) { DMA_XF(s + 1); } else { STAGE_ES(0); } // fuse B prologue
    const float* Xf = (const float*)Es[s & 1];
    ushort tmp[8] __attribute__((aligned(16)));
#pragma unroll
    for (int e = 0; e < 8; ++e) tmp[e] = bf16rne(Xf[(w * 8 + e) * 64 + lane]);
    *(uint4*)&Xbf[((size_t)(s * 8 + w) * 64 + lane) * 8] = *(uint4*)tmp;
  }
  asm volatile("s_waitcnt lgkmcnt(0)" ::: "memory"); // my Xbf writes landed
  __builtin_amdgcn_sched_barrier(0);

  // ---- Phase B: 32 pipelined phases (sweep = g>>4 [512 codes], ch = g&15) ----
  f16v zero16;
#pragma unroll
  for (int i = 0; i < 16; ++i) zero16[i] = 0.f;
  f16v acc[2][2];                                    // [kj codes][mi pos]

#pragma unroll 1
  for (int g = 0; g < 32; ++g) {
    asm volatile("s_waitcnt vmcnt(0)" ::: "memory"); // my STAGE(g) landed
    __builtin_amdgcn_sched_barrier(0);
    __builtin_amdgcn_s_barrier();                    // buf[g&1] full, prev reads done
    __builtin_amdgcn_sched_barrier(0);
    if (g < 31) { STAGE_ES(g + 1); }

    const int ch = g & 15, buf = g & 1;
    if (ch == 0) {
#pragma unroll
      for (int kj = 0; kj < 2; ++kj)
#pragma unroll
        for (int mi = 0; mi < 2; ++mi) acc[kj][mi] = zero16;
    }
    s8v a_[2], b_[2];
#pragma unroll
    for (int mi = 0; mi < 2; ++mi)                   // pos-frag: 32 pos x 16 d
      a_[mi] = *(const s8v*)&Xbf[((size_t)(ch * 2 + hi) * 64 + mi * 32 + l31) * 8];
#pragma unroll
    for (int kj = 0; kj < 2; ++kj)                   // code-frag: 32 codes x 16 d
      b_[kj] = *(const s8v*)&Es[buf][((size_t)hi * 512 + w * 64 + kj * 32 + l31) * 8];
#pragma unroll
    for (int kj = 0; kj < 2; ++kj)
#pragma unroll
      for (int mi = 0; mi < 2; ++mi)                 // SWAPPED: rows=codes
        acc[kj][mi] = __builtin_amdgcn_mfma_f32_32x32x16_bf16(
            b_[kj], a_[mi], acc[kj][mi], 0, 0, 0);

    if (ch == 15) {                                  // per-sweep epilogue
      const int kh = (g >> 4) * 512;
#pragma unroll
      for (int mi = 0; mi < 2; ++mi) {               // pos = mi*32 + l31
        float bv = 3.4e38f;
        int bk = 0;
#pragma unroll
        for (int kj = 0; kj < 2; ++kj)               // in-lane codes ascending:
#pragma unroll
          for (int r = 0; r < 16; ++r) {             // strict < = first-min
            int code = kh + w * 64 + kj * 32 + 4 * hi + (r & 3) + 8 * (r >> 2);
            float sc = __fadd_rn(e2s[code], -2.f * acc[kj][mi][r]);
            if (sc < bv) { bv = sc; bk = code; }
          }
        float ob = __shfl_xor(bv, 32, 64);           // merge hi-partner
        int   ok = __shfl_xor(bk, 32, 64);
        if (ob < bv || (ob == bv && ok < bk)) { bv = ob; bk = ok; }
        if (hi == 0)
          atomicMin(&bests[mi * 32 + l31],
                    ((unsigned long long)fkey(bv) << 32) | (unsigned)bk);
      }
    }
  }

  // ---- Phase C: prefetch latent, then gather + ST output + loss ----
  const int posq = t & 15;                           // pos-group of 4
  const int drow = t >> 4;                           // 0..31 d-slice
  const float* Lb2 = Lb + posq * 4;
  float4 x[8];
#pragma unroll
  for (int it = 0; it < 8; ++it)                     // independent of bests
    x[it] = *(const float4*)(Lb2 + (size_t)(it * 32 + drow) * HW_);
  __syncthreads();                                   // bests final (+drains x)
  int kk[4];
#pragma unroll
  for (int e = 0; e < 4; ++e)
    kk[e] = (int)(unsigned)(bests[posq * 4 + e] & 0xFFFFFFFFull);
  float* Ob = out + (size_t)b * (D_ * HW_) + hw0 + posq * 4;
  float part = 0.f;
#pragma unroll 2
  for (int it = 0; it < 8; ++it) {
    int d = it * 32 + drow;
    float4 xx = x[it];
    float4 o;
    float qv, df;
    qv = cb[(size_t)kk[0] * 256 + d]; df = __fsub_rn(qv, xx.x); o.x = __fadd_rn(xx.x, df); part = fmaf(df, df, part);
    qv = cb[(size_t)kk[1] * 256 + d]; df = __fsub_rn(qv, xx.y); o.y = __fadd_rn(xx.y, df); part = fmaf(df, df, part);
    qv = cb[(size_t)kk[2] * 256 + d]; df = __fsub_rn(qv, xx.z); o.z = __fadd_rn(xx.z, df); part = fmaf(df, df, part);
    qv = cb[(size_t)kk[3] * 256 + d]; df = __fsub_rn(qv, xx.w); o.w = __fadd_rn(xx.w, df); part = fmaf(df, df, part);
    *(float4*)(Ob + (size_t)d * HW_) = o;            // x + (q - x), NOT q
  }
#pragma unroll
  for (int off = 32; off > 0; off >>= 1) part += __shfl_down(part, off, 64);
  if (lane == 0) red[w] = part;
  __syncthreads();
  if (t == 0) {
    float tot = 0.f;
#pragma unroll
    for (int i = 0; i < 8; ++i) tot += red[i];
    atomicAdd(loss, tot * (1.25f / 8388608.0f));
  }
}

extern "C" void kernel_launch(void* const* d_in, const int* in_sizes, int n_in,
                              void* d_out, int out_size, void* d_ws, size_t ws_size,
                              hipStream_t stream) {
  const float* latent = (const float*)d_in[0];
  const float* cb     = (const float*)d_in[1];
  float* out  = (float*)d_out;
  float* loss = out + (size_t)N_ * D_;             // element 8,388,608
  ushort* Ebf = (ushort*)d_ws;                     // 512 KB chunk-planar bf16
  float*  e2  = (float*)((char*)d_ws + (size_t)K_ * D_ * sizeof(ushort));

  hipLaunchKernelGGL(k_eprep, dim3(128), dim3(256), 0, stream, cb, Ebf, e2, loss);
  hipLaunchKernelGGL(k_fused, dim3(512), dim3(512), 0, stream,
                     latent, cb, Ebf, e2, out, loss);
}

// Round 8
// 119.951 us; speedup vs baseline: 1.1501x; 1.1501x over previous
//
#include <hip/hip_runtime.h>
#include <stdint.h>

// VectorQuantizer on MI355X — round 14: ablate the Es LDS staging entirely.
// R7=56, R11=57, R12=55, R13~55+spill: four phase-B schedules, same time,
// all pipes <35% -> scheduling variables are insensitive. The one shared
// element: the global->LDS->reg staging round-trip + its sync coupling.
// R14 = R12's proven residency (8-wave blocks, 2 blk/CU) with B-fragments
// read DIRECTLY from L2-resident Ebf into registers (256 B contiguous per
// 16-lane q-group), 1-chunk prefetch, ZERO barriers in the K-loop. Register
// budget ~95 live < 128 cap (R9's confound was 160 live -> spill; acc is
// 32 regs here, epilogue light). LDS ~55 KB (Xbf 32 + Xf 17.4 + e2s 4).
// Numerics bit-identical to R12: same 16x16x32 MFMA, same ch=0..7 chain,
// same fadd(e2,-2*dot), same first-min {fkey|k} -> absmax must stay
// 0.001930237 exactly (tripwire).
// Pre-committed read: 35-45us -> staging was the cost; 65-80us -> L2
// latency is the wall; ~55us -> phase B exonerated, ablate A/C next.
// k_eprep: reads made wave-contiguous (dq fast over lanes), math untouched.
// latent [32,256,1024] fp32, codebook [1024,256] fp32.
// ws = [ Ebf bf16 chunk-planar [dq32][code1024][8] (512 KB) | e2 f32[1024] ].

#define D_   256
#define HW_  1024
#define N_   32768
#define K_   1024

typedef __attribute__((ext_vector_type(8))) short  s8v;   // 8 bf16 (4 VGPR)
typedef __attribute__((ext_vector_type(4))) float  f4v;   // MFMA acc

__device__ __forceinline__ ushort bf16rne(float x) {
  unsigned u = __float_as_uint(x);
  return (ushort)((u + 0x7FFFu + ((u >> 16) & 1u)) >> 16);
}

// monotone map: unsigned order of key == float order (handles negatives)
__device__ __forceinline__ unsigned fkey(float f) {
  unsigned u = __float_as_uint(f);
  return u ^ (unsigned)(((int)u >> 31) | 0x80000000);
}

// ---------- codebook -> bf16 chunk-planar Ebf + numpy-pairwise e2 + loss=0 ----------
// Same math/outputs as R12; convert-read mapping swapped so a wave reads
// 1 KB contiguous per row (dq fast across lanes) instead of 16x32B scatter.
__global__ __launch_bounds__(256) void k_eprep(const float* __restrict__ cb,
                                               ushort* __restrict__ Ebf,
                                               float* __restrict__ e2,
                                               float* __restrict__ loss) {
  const int t = threadIdx.x, blk = blockIdx.x;   // 128 blocks x 8 codes
  if (blk == 0 && t == 0) *loss = 0.f;
  {
    int dq = t & 31, cl = t >> 5;                // dq fast -> coalesced reads
    const float* src = cb + (size_t)(blk * 8 + cl) * 256 + dq * 8;
    float4 v0 = ((const float4*)src)[0], v1 = ((const float4*)src)[1];
    ushort tmp[8] __attribute__((aligned(16)));
    tmp[0] = bf16rne(v0.x); tmp[1] = bf16rne(v0.y);
    tmp[2] = bf16rne(v0.z); tmp[3] = bf16rne(v0.w);
    tmp[4] = bf16rne(v1.x); tmp[5] = bf16rne(v1.y);
    tmp[6] = bf16rne(v1.z); tmp[7] = bf16rne(v1.w);
    *(uint4*)(Ebf + ((size_t)dq * 1024 + blk * 8 + cl) * 8) = *(uint4*)tmp;
  }
  // e2 numpy-pairwise: 16 lanes/row, butterfly reproduces pairwise tree
  if (t < 128) {
    const int row = blk * 8 + (t >> 4);
    const int sub = t & 15, j = sub & 7, h = sub >> 3;
    const float* base = cb + row * 256 + h * 128 + j;
    float r = __fmul_rn(base[0], base[0]);
    for (int i = 1; i < 16; ++i) {
      float v = base[8 * i];
      r = __fadd_rn(r, __fmul_rn(v, v));
    }
#pragma unroll
    for (int m = 1; m < 16; m <<= 1) r = __fadd_rn(r, __shfl_xor(r, m, 64));
    if (sub == 0) e2[row] = r;
  }
}

// ---------- fused: convert + MFMA-argmin over K=1024 + gather + out + loss ----------
// Grid 512 tiles (64 pos, hw-contiguous). Block 512 = 8 waves.
// LDS: Xbf 32 KB [dq32][pos64][8]; Xf 17.4 KB ([64][68] f32, phase-A only);
// e2s 4 KB; bests 512 B -> ~55 KB -> 2 blocks/CU -> 16 waves/CU.
// Phase B: wave w covers codes {quarter*256 + w*32 .. +31}; acc[2][4]
// swapped (rows=codes); b-frags from global Ebf, 1-deep prefetch, no
// barriers; per-quarter light epilogue (2 shuffles) -> LDS atomicMin.
__global__ __launch_bounds__(512, 4) void k_fused(
    const float* __restrict__ latent, const float* __restrict__ cb,
    const ushort* __restrict__ Ebf, const float* __restrict__ e2g,
    float* __restrict__ out, float* __restrict__ loss) {
  __shared__ alignas(16) ushort Xbf[32 * 64 * 8];    // 32 KB
  __shared__ alignas(16) float Xf[64 * 68];          // 17.4 KB (phase A)
  __shared__ alignas(16) float e2s[1024];            // 4 KB
  __shared__ unsigned long long bests[64];           // 512 B
  __shared__ float red[8];

  const int t = threadIdx.x, tile = blockIdx.x;      // 512 tiles x 64 pos
  const int b = tile >> 4, hw0 = (tile & 15) * 64;
  const int lane = t & 63, w = t >> 6;               // wave 0..7
  const int lrow = lane & 15, q = lane >> 4;

  ((float2*)e2s)[t] = ((const float2*)e2g)[t];       // 1024 floats, 512 thr
  if (t < 64) bests[t] = ~0ull;

  // ---- Phase A: latent tile -> Xbf (bf16, chunk-planar), via Xf ----
  const float* Lb = latent + (size_t)b * (D_ * HW_) + hw0;
  for (int s = 0; s < 4; ++s) {                      // slabs of 64 d
    __syncthreads();
#pragma unroll
    for (int it = 0; it < 2; ++it) {                 // [64 d][64 hw] float4
      int id = it * 512 + t;
      int d = id >> 4, hq = id & 15;
      *(float4*)&Xf[d * 68 + hq * 4] =
          *(const float4*)(Lb + (size_t)(s * 64 + d) * HW_ + hq * 4);
    }
    __syncthreads();
    {                                                // transpose-convert
      int pos = t & 63, dqs = t >> 6;                // dqs 0..7 in slab
      ushort tmp[8] __attribute__((aligned(16)));
#pragma unroll
      for (int e = 0; e < 8; ++e) tmp[e] = bf16rne(Xf[(dqs * 8 + e) * 68 + pos]);
      *(uint4*)&Xbf[((size_t)(s * 8 + dqs) * 64 + pos) * 8] = *(uint4*)tmp;
    }
  }
  __syncthreads();                                   // Xbf/e2s/bests ready

  // ---- Phase B: barrier-free K-loop; b-frags direct from L2-resident Ebf ----
  // b-address for (chunk ch, quarter kq): lanes of a q-group read 16
  // consecutive codes x 16 B = 256 B contiguous.
  f4v acc[2][4];                                     // [code-sub kj][pos-sub mi]
  s8v bcur[2];
#pragma unroll
  for (int kj = 0; kj < 2; ++kj)                     // prologue: g=0 frags
    bcur[kj] = *(const s8v*)(Ebf + ((size_t)q * 1024 + w * 32 + kj * 16 + lrow) * 8);

#pragma unroll 1
  for (int g = 0; g < 32; ++g) {                     // quarter = g>>3, ch = g&7
    const int ch = g & 7;
    if (ch == 0) {
#pragma unroll
      for (int kj = 0; kj < 2; ++kj)
#pragma unroll
        for (int mi = 0; mi < 4; ++mi) acc[kj][mi] = (f4v){0.f, 0.f, 0.f, 0.f};
    }
    s8v bnxt[2];
    if (g < 31) {
      const int chN = (g + 1) & 7, kqN = ((g + 1) >> 3) << 8;
#pragma unroll
      for (int kj = 0; kj < 2; ++kj)                 // prefetch next chunk (L2)
        bnxt[kj] = *(const s8v*)(Ebf +
            ((size_t)(chN * 4 + q) * 1024 + kqN + w * 32 + kj * 16 + lrow) * 8);
    }
    s8v a_[4];
#pragma unroll
    for (int mi = 0; mi < 4; ++mi)
      a_[mi] = *(const s8v*)&Xbf[((size_t)(ch * 4 + q) * 64 + mi * 16 + lrow) * 8];
#pragma unroll
    for (int kj = 0; kj < 2; ++kj)
#pragma unroll
      for (int mi = 0; mi < 4; ++mi)                 // SWAPPED: rows=codes
        acc[kj][mi] = __builtin_amdgcn_mfma_f32_16x16x32_bf16(
            bcur[kj], a_[mi], acc[kj][mi], 0, 0, 0);

    if (ch == 7) {                                   // per-quarter epilogue
      const int kq = (g >> 3) << 8;
#pragma unroll
      for (int mi = 0; mi < 4; ++mi) {               // pos = mi*16+lrow
        float bv = 3.4e38f;
        int bk = 0;
#pragma unroll
        for (int kj = 0; kj < 2; ++kj)               // ascending code order:
#pragma unroll
          for (int reg = 0; reg < 4; ++reg) {        // first-min on ties
            int code = kq + w * 32 + kj * 16 + q * 4 + reg;
            float s = __fadd_rn(e2s[code], -2.f * acc[kj][mi][reg]);
            if (s < bv) { bv = s; bk = code; }
          }
#pragma unroll
        for (int m = 16; m < 64; m <<= 1) {          // reduce over q: 2 steps
          float ob = __shfl_xor(bv, m, 64);
          int ok = __shfl_xor(bk, m, 64);
          if (ob < bv || (ob == bv && ok < bk)) { bv = ob; bk = ok; }
        }
        if (q == 0)
          atomicMin(&bests[mi * 16 + lrow],
                    ((unsigned long long)fkey(bv) << 32) | (unsigned)bk);
      }
    }
    if (g < 31) { bcur[0] = bnxt[0]; bcur[1] = bnxt[1]; }
  }
  __syncthreads();                                   // bests final

  // ---- Phase C: gather + straight-through output + loss (R12 verbatim) ----
  const int posq = t & 15;                           // pos-group of 4
  const int drow = t >> 4;                           // 0..31 d-slice
  int kk[4];
#pragma unroll
  for (int e = 0; e < 4; ++e)
    kk[e] = (int)(unsigned)(bests[posq * 4 + e] & 0xFFFFFFFFull);
  float* Ob = out + (size_t)b * (D_ * HW_) + hw0 + posq * 4;
  const float* Lb2 = Lb + posq * 4;
  float part = 0.f;
#pragma unroll 2
  for (int it = 0; it < 8; ++it) {
    int d = it * 32 + drow;
    float4 x = *(const float4*)(Lb2 + (size_t)d * HW_);
    float4 o;
    float qv, df;
    qv = cb[(size_t)kk[0] * 256 + d]; df = __fsub_rn(qv, x.x); o.x = __fadd_rn(x.x, df); part = fmaf(df, df, part);
    qv = cb[(size_t)kk[1] * 256 + d]; df = __fsub_rn(qv, x.y); o.y = __fadd_rn(x.y, df); part = fmaf(df, df, part);
    qv = cb[(size_t)kk[2] * 256 + d]; df = __fsub_rn(qv, x.z); o.z = __fadd_rn(x.z, df); part = fmaf(df, df, part);
    qv = cb[(size_t)kk[3] * 256 + d]; df = __fsub_rn(qv, x.w); o.w = __fadd_rn(x.w, df); part = fmaf(df, df, part);
    *(float4*)(Ob + (size_t)d * HW_) = o;            // x + (q - x), NOT q
  }
#pragma unroll
  for (int off = 32; off > 0; off >>= 1) part += __shfl_down(part, off, 64);
  if (lane == 0) red[w] = part;
  __syncthreads();
  if (t == 0) {
    float tot = 0.f;
#pragma unroll
    for (int i = 0; i < 8; ++i) tot += red[i];
    atomicAdd(loss, tot * (1.25f / 8388608.0f));
  }
}

extern "C" void kernel_launch(void* const* d_in, const int* in_sizes, int n_in,
                              void* d_out, int out_size, void* d_ws, size_t ws_size,
                              hipStream_t stream) {
  const float* latent = (const float*)d_in[0];
  const float* cb     = (const float*)d_in[1];
  float* out  = (float*)d_out;
  float* loss = out + (size_t)N_ * D_;             // element 8,388,608
  ushort* Ebf = (ushort*)d_ws;                     // 512 KB chunk-planar bf16
  float*  e2  = (float*)((char*)d_ws + (size_t)K_ * D_ * sizeof(ushort));

  hipLaunchKernelGGL(k_eprep, dim3(128), dim3(256), 0, stream, cb, Ebf, e2, loss);
  hipLaunchKernelGGL(k_fused, dim3(512), dim3(512), 0, stream,
                     latent, cb, Ebf, e2, out, loss);
}

// Round 9
// 110.679 us; speedup vs baseline: 1.2464x; 1.0838x over previous
//
#include <hip/hip_runtime.h>
#include <stdint.h>

// VectorQuantizer on MI355X — round 15: fix phase-C divergent gather + defer
// argmin reduce. R14 (48.5us) proved: staging ablation -7us; remaining time
// has no saturated pipe (all <=25%) -> transaction/latency costs. Chief
// suspect: phase-C cb gather = 32 scalar loads/thread, 64 divergent rows per
// wave instr (~8.4M L2 transactions/dispatch, invisible in FETCH_SIZE).
// R15: (1) re-map phase-C d-assignment (thread owns d-quads dq4=mit*32+
// (t>>4)) -> float4 gathers: 8 instr/thread, 16 rows x 64 B CONTIGUOUS
// segments per instr (lanes sharing posq read adjacent quads). x/out
// coalescing unchanged. q-outputs bit-identical; loss partition changes ->
// +-1 ulp on the single loss scalar only.
// (2) defer cross-lane argmin to ONE 2-step shuffle + atomicMin per mi at
// K-loop end (per-lane running best across quarters; strict < on ascending
// codes = same first-min; min associative => same bests).
// Phase A, B-core, k_eprep: R14 verbatim. Spill tripwire: WRITE==32.8MB.
// latent [32,256,1024] fp32, codebook [1024,256] fp32.
// ws = [ Ebf bf16 chunk-planar [dq32][code1024][8] (512 KB) | e2 f32[1024] ].

#define D_   256
#define HW_  1024
#define N_   32768
#define K_   1024

typedef __attribute__((ext_vector_type(8))) short  s8v;   // 8 bf16 (4 VGPR)
typedef __attribute__((ext_vector_type(4))) float  f4v;   // MFMA acc

__device__ __forceinline__ ushort bf16rne(float x) {
  unsigned u = __float_as_uint(x);
  return (ushort)((u + 0x7FFFu + ((u >> 16) & 1u)) >> 16);
}

// monotone map: unsigned order of key == float order (handles negatives)
__device__ __forceinline__ unsigned fkey(float f) {
  unsigned u = __float_as_uint(f);
  return u ^ (unsigned)(((int)u >> 31) | 0x80000000);
}

// ---------- codebook -> bf16 chunk-planar Ebf + numpy-pairwise e2 + loss=0 ----------
// (R14 verbatim)
__global__ __launch_bounds__(256) void k_eprep(const float* __restrict__ cb,
                                               ushort* __restrict__ Ebf,
                                               float* __restrict__ e2,
                                               float* __restrict__ loss) {
  const int t = threadIdx.x, blk = blockIdx.x;   // 128 blocks x 8 codes
  if (blk == 0 && t == 0) *loss = 0.f;
  {
    int dq = t & 31, cl = t >> 5;                // dq fast -> coalesced reads
    const float* src = cb + (size_t)(blk * 8 + cl) * 256 + dq * 8;
    float4 v0 = ((const float4*)src)[0], v1 = ((const float4*)src)[1];
    ushort tmp[8] __attribute__((aligned(16)));
    tmp[0] = bf16rne(v0.x); tmp[1] = bf16rne(v0.y);
    tmp[2] = bf16rne(v0.z); tmp[3] = bf16rne(v0.w);
    tmp[4] = bf16rne(v1.x); tmp[5] = bf16rne(v1.y);
    tmp[6] = bf16rne(v1.z); tmp[7] = bf16rne(v1.w);
    *(uint4*)(Ebf + ((size_t)dq * 1024 + blk * 8 + cl) * 8) = *(uint4*)tmp;
  }
  // e2 numpy-pairwise: 16 lanes/row, butterfly reproduces pairwise tree
  if (t < 128) {
    const int row = blk * 8 + (t >> 4);
    const int sub = t & 15, j = sub & 7, h = sub >> 3;
    const float* base = cb + row * 256 + h * 128 + j;
    float r = __fmul_rn(base[0], base[0]);
    for (int i = 1; i < 16; ++i) {
      float v = base[8 * i];
      r = __fadd_rn(r, __fmul_rn(v, v));
    }
#pragma unroll
    for (int m = 1; m < 16; m <<= 1) r = __fadd_rn(r, __shfl_xor(r, m, 64));
    if (sub == 0) e2[row] = r;
  }
}

// ---------- fused: convert + MFMA-argmin over K=1024 + gather + out + loss ----------
// Grid 512 tiles (64 pos, hw-contiguous). Block 512 = 8 waves.
// LDS ~55 KB (Xbf 32 + Xf 17.4 + e2s 4) -> 2 blocks/CU -> 16 waves/CU.
// Phase B: barrier-free, b-frags direct from L2-resident Ebf, 1-deep
// prefetch, acc[2][4] swapped (rows=codes); per-lane running argmin,
// single final reduce.
__global__ __launch_bounds__(512, 4) void k_fused(
    const float* __restrict__ latent, const float* __restrict__ cb,
    const ushort* __restrict__ Ebf, const float* __restrict__ e2g,
    float* __restrict__ out, float* __restrict__ loss) {
  __shared__ alignas(16) ushort Xbf[32 * 64 * 8];    // 32 KB
  __shared__ alignas(16) float Xf[64 * 68];          // 17.4 KB (phase A)
  __shared__ alignas(16) float e2s[1024];            // 4 KB
  __shared__ unsigned long long bests[64];           // 512 B
  __shared__ float red[8];

  const int t = threadIdx.x, tile = blockIdx.x;      // 512 tiles x 64 pos
  const int b = tile >> 4, hw0 = (tile & 15) * 64;
  const int lane = t & 63, w = t >> 6;               // wave 0..7
  const int lrow = lane & 15, q = lane >> 4;

  ((float2*)e2s)[t] = ((const float2*)e2g)[t];       // 1024 floats, 512 thr
  if (t < 64) bests[t] = ~0ull;

  // ---- Phase A: latent tile -> Xbf (bf16, chunk-planar), via Xf ----
  const float* Lb = latent + (size_t)b * (D_ * HW_) + hw0;
  for (int s = 0; s < 4; ++s) {                      // slabs of 64 d
    __syncthreads();
#pragma unroll
    for (int it = 0; it < 2; ++it) {                 // [64 d][64 hw] float4
      int id = it * 512 + t;
      int d = id >> 4, hq = id & 15;
      *(float4*)&Xf[d * 68 + hq * 4] =
          *(const float4*)(Lb + (size_t)(s * 64 + d) * HW_ + hq * 4);
    }
    __syncthreads();
    {                                                // transpose-convert
      int pos = t & 63, dqs = t >> 6;                // dqs 0..7 in slab
      ushort tmp[8] __attribute__((aligned(16)));
#pragma unroll
      for (int e = 0; e < 8; ++e) tmp[e] = bf16rne(Xf[(dqs * 8 + e) * 68 + pos]);
      *(uint4*)&Xbf[((size_t)(s * 8 + dqs) * 64 + pos) * 8] = *(uint4*)tmp;
    }
  }
  __syncthreads();                                   // Xbf/e2s/bests ready

  // ---- Phase B: barrier-free K-loop; b-frags direct from L2-resident Ebf ----
  f4v acc[2][4];                                     // [code-sub kj][pos-sub mi]
  float bv[4];                                       // per-lane running argmin
  int bk[4];
#pragma unroll
  for (int mi = 0; mi < 4; ++mi) { bv[mi] = 3.4e38f; bk[mi] = 0; }

  s8v bcur[2];
#pragma unroll
  for (int kj = 0; kj < 2; ++kj)                     // prologue: g=0 frags
    bcur[kj] = *(const s8v*)(Ebf + ((size_t)q * 1024 + w * 32 + kj * 16 + lrow) * 8);

#pragma unroll 1
  for (int g = 0; g < 32; ++g) {                     // quarter = g>>3, ch = g&7
    const int ch = g & 7;
    if (ch == 0) {
#pragma unroll
      for (int kj = 0; kj < 2; ++kj)
#pragma unroll
        for (int mi = 0; mi < 4; ++mi) acc[kj][mi] = (f4v){0.f, 0.f, 0.f, 0.f};
    }
    s8v bnxt[2];
    if (g < 31) {
      const int chN = (g + 1) & 7, kqN = ((g + 1) >> 3) << 8;
#pragma unroll
      for (int kj = 0; kj < 2; ++kj)                 // prefetch next chunk (L2)
        bnxt[kj] = *(const s8v*)(Ebf +
            ((size_t)(chN * 4 + q) * 1024 + kqN + w * 32 + kj * 16 + lrow) * 8);
    }
    s8v a_[4];
#pragma unroll
    for (int mi = 0; mi < 4; ++mi)
      a_[mi] = *(const s8v*)&Xbf[((size_t)(ch * 4 + q) * 64 + mi * 16 + lrow) * 8];
#pragma unroll
    for (int kj = 0; kj < 2; ++kj)
#pragma unroll
      for (int mi = 0; mi < 4; ++mi)                 // SWAPPED: rows=codes
        acc[kj][mi] = __builtin_amdgcn_mfma_f32_16x16x32_bf16(
            bcur[kj], a_[mi], acc[kj][mi], 0, 0, 0);

    if (ch == 7) {                                   // per-quarter scoring only
      const int kq = (g >> 3) << 8;
#pragma unroll
      for (int mi = 0; mi < 4; ++mi)
#pragma unroll
        for (int kj = 0; kj < 2; ++kj)               // ascending code order:
#pragma unroll
          for (int reg = 0; reg < 4; ++reg) {        // strict < = first-min
            int code = kq + w * 32 + kj * 16 + q * 4 + reg;
            float s = __fadd_rn(e2s[code], -2.f * acc[kj][mi][reg]);
            if (s < bv[mi]) { bv[mi] = s; bk[mi] = code; }
          }
    }
    if (g < 31) { bcur[0] = bnxt[0]; bcur[1] = bnxt[1]; }
  }
  // single final cross-lane reduce + cross-wave merge (min is associative)
#pragma unroll
  for (int mi = 0; mi < 4; ++mi) {
    float v = bv[mi];
    int k2 = bk[mi];
#pragma unroll
    for (int m = 16; m < 64; m <<= 1) {              // reduce over q: 2 steps
      float ov = __shfl_xor(v, m, 64);
      int ok = __shfl_xor(k2, m, 64);
      if (ov < v || (ov == v && ok < k2)) { v = ov; k2 = ok; }
    }
    if (q == 0)
      atomicMin(&bests[mi * 16 + lrow],
                ((unsigned long long)fkey(v) << 32) | (unsigned)k2);
  }
  __syncthreads();                                   // bests final

  // ---- Phase C: float4 gathers + straight-through output + loss ----
  const int posq = t & 15;                           // pos-group of 4
  const int dsub = t >> 4;                           // 0..31
  int kk[4];
#pragma unroll
  for (int e = 0; e < 4; ++e)
    kk[e] = (int)(unsigned)(bests[posq * 4 + e] & 0xFFFFFFFFull);
  float* Ob = out + (size_t)b * (D_ * HW_) + hw0 + posq * 4;
  const float* Lb2 = Lb + posq * 4;
  float part = 0.f;
#pragma unroll
  for (int mit = 0; mit < 2; ++mit) {
    const int dq4 = mit * 32 + dsub;                 // d-quad 0..63
    float4 qv4[4];
#pragma unroll
    for (int e = 0; e < 4; ++e)                      // 64 B contig per row/4 lanes
      qv4[e] = *(const float4*)(cb + (size_t)kk[e] * 256 + dq4 * 4);
#pragma unroll
    for (int j = 0; j < 4; ++j) {
      const int d = dq4 * 4 + j;
      float4 x = *(const float4*)(Lb2 + (size_t)d * HW_);
      float4 o;
      float qv, df;
      qv = ((const float*)&qv4[0])[j]; df = __fsub_rn(qv, x.x); o.x = __fadd_rn(x.x, df); part = fmaf(df, df, part);
      qv = ((const float*)&qv4[1])[j]; df = __fsub_rn(qv, x.y); o.y = __fadd_rn(x.y, df); part = fmaf(df, df, part);
      qv = ((const float*)&qv4[2])[j]; df = __fsub_rn(qv, x.z); o.z = __fadd_rn(x.z, df); part = fmaf(df, df, part);
      qv = ((const float*)&qv4[3])[j]; df = __fsub_rn(qv, x.w); o.w = __fadd_rn(x.w, df); part = fmaf(df, df, part);
      *(float4*)(Ob + (size_t)d * HW_) = o;          // x + (q - x), NOT q
    }
  }
#pragma unroll
  for (int off = 32; off > 0; off >>= 1) part += __shfl_down(part, off, 64);
  if (lane == 0) red[w] = part;
  __syncthreads();
  if (t == 0) {
    float tot = 0.f;
#pragma unroll
    for (int i = 0; i < 8; ++i) tot += red[i];
    atomicAdd(loss, tot * (1.25f / 8388608.0f));
  }
}

extern "C" void kernel_launch(void* const* d_in, const int* in_sizes, int n_in,
                              void* d_out, int out_size, void* d_ws, size_t ws_size,
                              hipStream_t stream) {
  const float* latent = (const float*)d_in[0];
  const float* cb     = (const float*)d_in[1];
  float* out  = (float*)d_out;
  float* loss = out + (size_t)N_ * D_;             // element 8,388,608
  ushort* Ebf = (ushort*)d_ws;                     // 512 KB chunk-planar bf16
  float*  e2  = (float*)((char*)d_ws + (size_t)K_ * D_ * sizeof(ushort));

  hipLaunchKernelGGL(k_eprep, dim3(128), dim3(256), 0, stream, cb, Ebf, e2, loss);
  hipLaunchKernelGGL(k_fused, dim3(512), dim3(512), 0, stream,
                     latent, cb, Ebf, e2, out, loss);
}